// Round 1
// baseline (9.277 us; speedup 1.0000x reference)
//
#include <hip/hip_runtime.h>
#include <math.h>

// KeplerDiffEq: 4 orbits, 6 outputs each (dr[3], ddr[3]), all f32.
// Inputs (in setup_inputs order):
//   0: a            (4)
//   1: e            (4)
//   2: i            (4)
//   3: omega        (4)
//   4: Omega        (4)
//   5: mean_motion  (4)
//   6: mean_anomaly (1)  -- scalar
//   7: x            (4*6)
// Output: (4,6) f32 row-major = concat([dr, ddr], axis=-1)

#define MU 3.0f

__global__ __launch_bounds__(64) void KeplerDiffEq_kernel(
    const float* __restrict__ a,
    const float* __restrict__ e,
    const float* __restrict__ inc,
    const float* __restrict__ omega,
    const float* __restrict__ Omega,
    const float* __restrict__ mm,
    const float* __restrict__ M0,
    const float* __restrict__ x,
    float* __restrict__ out)
{
    const int row = threadIdx.x;
    if (row >= 4) return;

    const float ev = e[row];
    const float M  = M0[0];

    // Full Newton on E - e*sin(E) - M = 0, E0 = M.
    // Reference uses a 0.01-damped version of the same iteration for 2000
    // steps -> converges to this root to ~1e-9; threshold is 3.45e-2.
    float E = M;
    #pragma unroll
    for (int it = 0; it < 8; ++it) {
        float s, c;
        __sincosf(E, &s, &c);
        const float f  = E - ev * s - M;
        const float fp = 1.0f - ev * c;
        E -= f / fp;
    }

    float sE, cE;
    __sincosf(E, &sE, &cE);

    const float av  = a[row];
    const float r_c = av * (1.0f - ev * cE);
    const float scaling = sqrtf(MU * av) / r_c;

    const float x_ = x[row * 6 + 0];
    const float y_ = x[row * 6 + 1];

    const float dx = -sE * scaling;
    const float dy = sqrtf(1.0f - ev * ev) * cE * scaling;

    float sw, cw, sW, cW, si, ci;
    __sincosf(omega[row], &sw, &cw);
    __sincosf(Omega[row], &sW, &cW);
    __sincosf(inc[row],   &si, &ci);

    const float c11 =  cw * cW - sw * sW * ci;
    const float c12 = -sw * cW - cw * sW * ci;
    const float c21 =  cw * sW + sw * cW * ci;
    const float c22 = -sw * sW + cw * cW * ci;
    const float c31 =  sw * si;
    const float c32 =  cw * si;

    const float r1 = c11 * x_ + c12 * y_;
    const float r2 = c21 * x_ + c22 * y_;
    const float r3 = c31 * x_ + c32 * y_;

    const float dr1 = c11 * dx + c12 * dy;
    const float dr2 = c21 * dx + c22 * dy;
    const float dr3 = c31 * dx + c32 * dy;

    const float n = mm[row];
    const float acc_scale = -(n * n) * (av * av * av) / (r_c * r_c);
    const float k = acc_scale / sqrtf(r1 * r1 + r2 * r2 + r3 * r3);

    float* o = out + row * 6;
    o[0] = dr1;
    o[1] = dr2;
    o[2] = dr3;
    o[3] = k * r1;
    o[4] = k * r2;
    o[5] = k * r3;
}

extern "C" void kernel_launch(void* const* d_in, const int* in_sizes, int n_in,
                              void* d_out, int out_size, void* d_ws, size_t ws_size,
                              hipStream_t stream) {
    const float* a     = (const float*)d_in[0];
    const float* e     = (const float*)d_in[1];
    const float* inc   = (const float*)d_in[2];
    const float* omega = (const float*)d_in[3];
    const float* Omega = (const float*)d_in[4];
    const float* mm    = (const float*)d_in[5];
    const float* M0    = (const float*)d_in[6];
    const float* x     = (const float*)d_in[7];
    float* out = (float*)d_out;

    KeplerDiffEq_kernel<<<1, 64, 0, stream>>>(a, e, inc, omega, Omega, mm, M0, x, out);
}